// Round 4
// baseline (142.459 us; speedup 1.0000x reference)
//
#include <hip/hip_runtime.h>
#include <hip/hip_bf16.h>
#include <stdint.h>

// Problem constants: B=4, CIN=COUT=256, H=W=64, 3x3, pad=1, stride=1, dil=1
#define KDIM 2304   // CIN * 9, GEMM K

typedef __bf16 bf16_t;
typedef bf16_t bf16x8 __attribute__((ext_vector_type(8)));
typedef float f32x4 __attribute__((ext_vector_type(4)));
typedef float f32x2 __attribute__((ext_vector_type(2)));

__device__ __forceinline__ float b2f_lo(uint32_t u) {
  union { uint32_t i; float f; } c; c.i = u << 16; return c.f;
}
__device__ __forceinline__ float b2f_hi(uint32_t u) {
  union { uint32_t i; float f; } c; c.i = u & 0xffff0000u; return c.f;
}
// pack 2 floats -> 2 bf16 (RNE), a in low half
__device__ __forceinline__ uint32_t pk_bf16(float a, float b) {
  __hip_bfloat162 h = __float22bfloat162_rn(make_float2(a, b));
  union { __hip_bfloat162 h; uint32_t u; } c; c.h = h; return c.u;
}

// async 16B global -> LDS (wave-uniform base + lane*16 contract)
__device__ __forceinline__ void g2lds16(const uint16_t* g, uint16_t* l) {
  __builtin_amdgcn_global_load_lds((const __attribute__((address_space(1))) void*)g,
                                   (__attribute__((address_space(3))) void*)l,
                                   16, 0, 0);
}

// ---------------- kernel 1: x [4][256][64][64] f32 -> xt [4][64][64][256] bf16
__global__ __launch_bounds__(256) void k_transpose(const float* __restrict__ x,
                                                   uint16_t* __restrict__ xt) {
  __shared__ float tile[32][33];
  int b = blockIdx.z;
  int c0 = blockIdx.y << 5;
  int s0 = blockIdx.x << 5;   // s = h*64+w
  int tid = threadIdx.x;
  int tx = tid & 31, ty = tid >> 5;
  const float* src = x + ((size_t)(b * 256 + c0)) * 4096 + s0;
#pragma unroll
  for (int i = 0; i < 4; ++i)
    tile[ty + i * 8][tx] = src[(size_t)(ty + i * 8) * 4096 + tx];  // [chan][spatial]
  __syncthreads();
  int cg = tid & 7, sp = tid >> 3;
  uint2 o;
  o.x = pk_bf16(tile[cg * 4 + 0][sp], tile[cg * 4 + 1][sp]);
  o.y = pk_bf16(tile[cg * 4 + 2][sp], tile[cg * 4 + 3][sp]);
  *(uint2*)&xt[((size_t)b * 4096 + s0 + sp) * 256 + c0 + cg * 4] = o;
}

// ---------------- kernel 2: weight [256][256][3][3] f32 -> wt [cout][k*256+c] bf16
__global__ __launch_bounds__(256) void k_wprep(const float* __restrict__ w,
                                               uint16_t* __restrict__ wt) {
  int t = blockIdx.x * 256 + threadIdx.x;   // exactly 256*2304 threads
  int cout = t / KDIM;
  int r = t - cout * KDIM;
  int k = r >> 8, c = r & 255;
  wt[t] = (uint16_t)(pk_bf16(w[((size_t)(cout * 256 + c)) * 9 + k], 0.f) & 0xffffu);
}

// ---------------- kernel 3: FUSED deform-im2col + GEMM
// C[m][n] = sum_k wt[m][k] * cols(n,k), cols computed on the fly into LDS.
// Tile: BM=128 x BN=64, BK=32. Grid 256(n) x 2(m) = 512 blocks = 2/CU.
// One block's 64 n-positions = one full (b, ho) output row (Wo=64).
// K order: tap-major (k = tap*256 + c); 8 BK-steps share one tap.
#define BM 128
#define BN 64
#define BK 32
__global__ __launch_bounds__(256) void k_fused(const uint16_t* __restrict__ xt,
                                               const uint16_t* __restrict__ A,
                                               const float* __restrict__ off,
                                               const float* __restrict__ msk,
                                               const float* __restrict__ bias,
                                               float* __restrict__ out) {
  __shared__ __align__(16) uint16_t As[BM * BK];  // 8 KB
  __shared__ __align__(16) uint16_t Bs[BN * BK];  // 4 KB
  __shared__ float s_off[18 * 64];                // 4.5 KB
  __shared__ float s_msk[9 * 64];                 // 2.25 KB

  int tid = threadIdx.x;
  int n0 = blockIdx.x << 6;
  int m0 = blockIdx.y << 7;
  int b = blockIdx.x >> 6;         // n0 >> 12
  int ho = blockIdx.x & 63;

  // stage this output row's offsets (18 ch x 64 wo) and masks (9 ch x 64 wo)
  const float* offb = off + (size_t)b * 18 * 4096 + ho * 64;
  for (int i = tid; i < 18 * 64; i += 256)
    s_off[i] = offb[(size_t)(i >> 6) * 4096 + (i & 63)];
  const float* mskb = msk + (size_t)b * 9 * 4096 + ho * 64;
  for (int i = tid; i < 9 * 64; i += 256)
    s_msk[i] = mskb[(size_t)(i >> 6) * 4096 + (i & 63)];
  __syncthreads();

  int lane = tid & 63, wv = tid >> 6;
  int wm = wv >> 1, wn = wv & 1;           // 2x2 wave grid: 64m x 32n
  int q = lane >> 4, r = lane & 15;

  f32x4 acc[4][2];
#pragma unroll
  for (int i = 0; i < 4; ++i)
#pragma unroll
    for (int j = 0; j < 2; ++j) acc[i][j] = f32x4{0.f, 0.f, 0.f, 0.f};

  // A staging (async): rows 0-63 and 64-127, 8 elems (16B) per thread
  const uint16_t* a0p = A + (size_t)(m0 + (tid >> 2)) * KDIM + (tid & 3) * 8;
  const uint16_t* a1p = A + (size_t)(m0 + 64 + (tid >> 2)) * KDIM + (tid & 3) * 8;
  uint16_t* as0 = &As[tid * 8];
  uint16_t* as1 = &As[2048 + tid * 8];

  // B staging (compute): thread -> position p, channel chunk cq*8
  int p = tid >> 2, cq = tid & 3;          // p = wo
  uint16_t* bs_dst = &Bs[tid * 8];         // = Bs[p*32 + cq*8]
  const uint16_t* xtb = xt + (size_t)b * 4096 * 256 + cq * 8;

  for (int tap = 0; tap < 9; ++tap) {
    int kh = tap / 3, kw = tap - kh * 3;
    float dy = s_off[(2 * tap) * 64 + p];
    float dx = s_off[(2 * tap + 1) * 64 + p];
    float mm = s_msk[tap * 64 + p];
    float sy = (float)(ho - 1 + kh) + dy;
    float sx = (float)(p - 1 + kw) + dx;
    float fy = floorf(sy), fx = floorf(sx);
    int y0 = (int)fy, x0 = (int)fx;
    float wy = sy - fy, wx = sx - fx;
    // mask-folded corner weights + clamped corner pointers
    float cw[4];
    const uint16_t* cp[4];
#pragma unroll
    for (int cy = 0; cy < 2; ++cy) {
#pragma unroll
      for (int cx = 0; cx < 2; ++cx) {
        int y = y0 + cy, x = x0 + cx;
        float w = (cy ? wy : 1.f - wy) * (cx ? wx : 1.f - wx) * mm;
        bool v = ((unsigned)y < 64u) && ((unsigned)x < 64u);
        w = v ? w : 0.f;
        int yc = min(max(y, 0), 63), xc = min(max(x, 0), 63);
        cw[cy * 2 + cx] = w;
        cp[cy * 2 + cx] = xtb + ((yc << 6) + xc) * 256;
      }
    }
    const uint16_t* abase0 = a0p + tap * 256;
    const uint16_t* abase1 = a1p + tap * 256;
#pragma unroll
    for (int st = 0; st < 8; ++st) {
      // A tile -> LDS (async DMA)
      g2lds16(abase0 + st * 32, as0);
      g2lds16(abase1 + st * 32, as1);
      // B: gather 4 corners (8 ch each), blend, pack, -> LDS
      const uint4 d0 = *(const uint4*)(cp[0] + st * 32);
      const uint4 d1 = *(const uint4*)(cp[1] + st * 32);
      const uint4 d2 = *(const uint4*)(cp[2] + st * 32);
      const uint4 d3 = *(const uint4*)(cp[3] + st * 32);
      f32x2 v0 = {0.f, 0.f}, v1 = {0.f, 0.f}, v2 = {0.f, 0.f}, v3 = {0.f, 0.f};
      f32x2 w0 = {cw[0], cw[0]}, w1 = {cw[1], cw[1]}, w2 = {cw[2], cw[2]}, w3 = {cw[3], cw[3]};
      v0 += w0 * f32x2{b2f_lo(d0.x), b2f_hi(d0.x)};
      v1 += w0 * f32x2{b2f_lo(d0.y), b2f_hi(d0.y)};
      v2 += w0 * f32x2{b2f_lo(d0.z), b2f_hi(d0.z)};
      v3 += w0 * f32x2{b2f_lo(d0.w), b2f_hi(d0.w)};
      v0 += w1 * f32x2{b2f_lo(d1.x), b2f_hi(d1.x)};
      v1 += w1 * f32x2{b2f_lo(d1.y), b2f_hi(d1.y)};
      v2 += w1 * f32x2{b2f_lo(d1.z), b2f_hi(d1.z)};
      v3 += w1 * f32x2{b2f_lo(d1.w), b2f_hi(d1.w)};
      v0 += w2 * f32x2{b2f_lo(d2.x), b2f_hi(d2.x)};
      v1 += w2 * f32x2{b2f_lo(d2.y), b2f_hi(d2.y)};
      v2 += w2 * f32x2{b2f_lo(d2.z), b2f_hi(d2.z)};
      v3 += w2 * f32x2{b2f_lo(d2.w), b2f_hi(d2.w)};
      v0 += w3 * f32x2{b2f_lo(d3.x), b2f_hi(d3.x)};
      v1 += w3 * f32x2{b2f_lo(d3.y), b2f_hi(d3.y)};
      v2 += w3 * f32x2{b2f_lo(d3.z), b2f_hi(d3.z)};
      v3 += w3 * f32x2{b2f_lo(d3.w), b2f_hi(d3.w)};
      uint4 o;
      o.x = pk_bf16(v0.x, v0.y);
      o.y = pk_bf16(v1.x, v1.y);
      o.z = pk_bf16(v2.x, v2.y);
      o.w = pk_bf16(v3.x, v3.y);
      *(uint4*)bs_dst = o;
      __syncthreads();
      // fragments + MFMA
      bf16x8 af[4], bfr[2];
#pragma unroll
      for (int mi = 0; mi < 4; ++mi)
        af[mi] = *(const bf16x8*)&As[(wm * 64 + mi * 16 + r) * BK + q * 8];
#pragma unroll
      for (int ni = 0; ni < 2; ++ni)
        bfr[ni] = *(const bf16x8*)&Bs[(wn * 32 + ni * 16 + r) * BK + q * 8];
#pragma unroll
      for (int mi = 0; mi < 4; ++mi)
#pragma unroll
        for (int ni = 0; ni < 2; ++ni)
          acc[mi][ni] = __builtin_amdgcn_mfma_f32_16x16x32_bf16(af[mi], bfr[ni], acc[mi][ni], 0, 0, 0);
      __syncthreads();
    }
  }

  // epilogue: C/D layout col = lane&15 (n), row = q*4 + j (m); direct store
#pragma unroll
  for (int mi = 0; mi < 4; ++mi) {
#pragma unroll
    for (int j = 0; j < 4; ++j) {
      int m = m0 + wm * 64 + mi * 16 + q * 4 + j;
      float bv = bias[m];
#pragma unroll
      for (int ni = 0; ni < 2; ++ni) {
        int n = n0 + wn * 32 + ni * 16 + r;
        int bb = n >> 12, pp = n & 4095;
        out[((size_t)(bb * 256 + m)) * 4096 + pp] = acc[mi][ni][j] + bv;
      }
    }
  }
}

extern "C" void kernel_launch(void* const* d_in, const int* in_sizes, int n_in,
                              void* d_out, int out_size, void* d_ws, size_t ws_size,
                              hipStream_t stream) {
  (void)in_sizes; (void)n_in; (void)out_size; (void)ws_size;
  const float* x      = (const float*)d_in[0];  // [4][256][64][64]
  const float* offset = (const float*)d_in[1];  // [4][18][64][64]
  const float* mask   = (const float*)d_in[2];  // [4][9][64][64]
  const float* weight = (const float*)d_in[3];  // [256][256][3][3]
  const float* bias   = (const float*)d_in[4];  // [256]
  float* out = (float*)d_out;                   // [4][256][64][64]

  uint8_t* ws = (uint8_t*)d_ws;
  uint16_t* xt = (uint16_t*)ws;                 // 8,388,608 B : NHWC bf16
  uint16_t* wt = (uint16_t*)(ws + 8388608);     // 1,179,648 B : [cout][k*256+c]

  k_transpose<<<dim3(128, 8, 4), 256, 0, stream>>>(x, xt);
  k_wprep<<<dim3(2304), 256, 0, stream>>>(weight, wt);
  k_fused<<<dim3(256, 2), 256, 0, stream>>>(xt, wt, offset, mask, bias, out);
}